// Round 9
// baseline (284.081 us; speedup 1.0000x reference)
//
#include <hip/hip_runtime.h>
#include <math.h>

#define HW 9216   // 96*96
#define NI 18     // 64-p steps per fallback-k3 block
#define PROW 72   // ushorts per P-row in fallback LDS

typedef __attribute__((ext_vector_type(8))) short bf16x8;
typedef __attribute__((ext_vector_type(4))) float f32x4;
typedef unsigned short ushort_t;
typedef unsigned int uint_t;

__device__ __forceinline__ ushort_t f2bf(float f) {
    union { float f; uint_t u; } v; v.f = f;
    uint_t u = v.u + 0x7FFF + ((v.u >> 16) & 1);   // RNE
    return (ushort_t)(u >> 16);
}

__device__ __forceinline__ uint_t cvtpk_bf16(float lo, float hi) {
    uint_t r;
    asm("v_cvt_pk_bf16_f32 %0, %1, %2" : "=v"(r) : "v"(lo), "v"(hi));
    return r;
}

// P = exp(S - m)/l = exp2(S*log2e + muS), muS = -(m + ln l)*log2e
__device__ __forceinline__ float pexp(float s, float mu) {
    return exp2f(fmaf(s, 1.44269504f, mu));
}

// ------------------------------------------------------------------
// k1: 1x1 conv -> Gbt[p][o] bf16 (p = w*96+h permuted, o contiguous)
//     + xtile[jt][c][32] bf16
// ------------------------------------------------------------------
__global__ __launch_bounds__(256) void k1_conv(
        const float* __restrict__ x, const float* __restrict__ wc,
        const float* __restrict__ bc, ushort_t* __restrict__ Gbt,
        ushort_t* __restrict__ xtile) {
    __shared__ float wt[256][32];          // [c][o] 32KB
    __shared__ float red[8][32][33];       // [cg][px][o] padded
    int t = threadIdx.x;
    int jt = blockIdx.x;
    for (int i = t; i < 256 * 32; i += 256) {
        int o = i >> 8, c = i & 255;       // wc is [o][c]
        wt[c][o] = wc[i];
    }
    __syncthreads();
    int px = t & 31, cg = t >> 5;
    int n = jt * 32 + px;
    float acc[32];
    #pragma unroll
    for (int o = 0; o < 32; ++o) acc[o] = 0.f;
    int c0 = cg * 32;
    ushort_t* xt_out = &xtile[(size_t)jt * 8192 + px];
    for (int cc = 0; cc < 32; ++cc) {
        int c = c0 + cc;
        float xv = x[c * HW + n];
        xt_out[c * 32] = f2bf(xv);         // fused xtile emission
        #pragma unroll
        for (int o4 = 0; o4 < 8; ++o4) {
            float4 wv = *(const float4*)&wt[c][o4 * 4];
            acc[o4*4+0] = fmaf(wv.x, xv, acc[o4*4+0]);
            acc[o4*4+1] = fmaf(wv.y, xv, acc[o4*4+1]);
            acc[o4*4+2] = fmaf(wv.z, xv, acc[o4*4+2]);
            acc[o4*4+3] = fmaf(wv.w, xv, acc[o4*4+3]);
        }
    }
    #pragma unroll
    for (int o = 0; o < 32; ++o) red[cg][px][o] = acc[o];
    __syncthreads();
    int px2 = t >> 3, o2 = (t & 7) * 4;
    float s[4] = {0.f, 0.f, 0.f, 0.f};
    #pragma unroll
    for (int g = 0; g < 8; ++g) {
        s[0] += red[g][px2][o2 + 0];
        s[1] += red[g][px2][o2 + 1];
        s[2] += red[g][px2][o2 + 2];
        s[3] += red[g][px2][o2 + 3];
    }
    int n2 = jt * 32 + px2;
    int h = n2 / 96, w = n2 % 96;
    int p = w * 96 + h;
    uint2 pk;
    pk.x = (uint_t)f2bf(s[0] + bc[o2+0]) | ((uint_t)f2bf(s[1] + bc[o2+1]) << 16);
    pk.y = (uint_t)f2bf(s[2] + bc[o2+2]) | ((uint_t)f2bf(s[3] + bc[o2+3]) << 16);
    *(uint2*)&Gbt[p * 32 + o2] = pk;
}

// ------------------------------------------------------------------
// k2: per-row online softmax stats of S = G^T G via bf16 MFMA.
// ------------------------------------------------------------------
__global__ __launch_bounds__(512) void k2_stats(
        const ushort_t* __restrict__ Gbt, float* __restrict__ m_part,
        float* __restrict__ l_part) {
    __shared__ float mred[2][64], lred[2][64];
    int t = threadIdx.x;
    int w = t >> 6, l = t & 63;
    int l15 = l & 15, lg = l >> 4;
    int jb = blockIdx.x % 144, qs = blockIdx.x / 144;
    int j0 = jb * 64;
    int rf = w & 3, qp = w >> 2;
    bf16x8 aj = *(const bf16x8*)&Gbt[(j0 + rf * 16 + l15) * 32 + lg * 8];
    float m[4], lsum[4];
    #pragma unroll
    for (int r = 0; r < 4; ++r) { m[r] = -INFINITY; lsum[r] = 0.f; }
    int qbeg = qs * 1152;
    for (int tq = 0; tq < 18; ++tq) {
        int q0 = qbeg + tq * 64;
        bf16x8 b0 = *(const bf16x8*)&Gbt[(q0 + qp * 32 + l15) * 32 + lg * 8];
        bf16x8 b1 = *(const bf16x8*)&Gbt[(q0 + qp * 32 + 16 + l15) * 32 + lg * 8];
        f32x4 s0 = {0.f,0.f,0.f,0.f}, s1 = {0.f,0.f,0.f,0.f};
        s0 = __builtin_amdgcn_mfma_f32_16x16x32_bf16(aj, b0, s0, 0, 0, 0);
        s1 = __builtin_amdgcn_mfma_f32_16x16x32_bf16(aj, b1, s1, 0, 0, 0);
        #pragma unroll
        for (int r = 0; r < 4; ++r) {
            float tm = fmaxf(s0[r], s1[r]);
            float nm = fmaxf(m[r], tm);
            lsum[r] = lsum[r] * __expf(m[r] - nm)
                    + __expf(s0[r] - nm) + __expf(s1[r] - nm);
            m[r] = nm;
        }
    }
    #pragma unroll
    for (int off = 1; off < 16; off <<= 1) {
        #pragma unroll
        for (int r = 0; r < 4; ++r) {
            float mo = __shfl_xor(m[r], off);
            float lo = __shfl_xor(lsum[r], off);
            float nm = fmaxf(m[r], mo);
            lsum[r] = lsum[r] * __expf(m[r] - nm) + lo * __expf(mo - nm);
            m[r] = nm;
        }
    }
    if (l15 == 0) {
        #pragma unroll
        for (int r = 0; r < 4; ++r) {
            mred[qp][rf * 16 + lg * 4 + r] = m[r];
            lred[qp][rf * 16 + lg * 4 + r] = lsum[r];
        }
    }
    __syncthreads();
    if (t < 64) {
        float m0 = mred[0][t], m1 = mred[1][t];
        float l0 = lred[0][t], l1 = lred[1][t];
        float nm = fmaxf(m0, m1);
        float lv = l0 * __expf(m0 - nm) + l1 * __expf(m1 - nm);
        m_part[qs * HW + j0 + t] = nm;
        l_part[qs * HW + j0 + t] = lv;
    }
}

// merge 8 q-split partials -> muS = -(m + ln l) * log2e
__global__ __launch_bounds__(256) void k2b_merge(
        const float* __restrict__ m_part, const float* __restrict__ l_part,
        float* __restrict__ muS) {
    int j = blockIdx.x * 256 + threadIdx.x;
    float nm = -INFINITY;
    #pragma unroll
    for (int s = 0; s < 8; ++s) nm = fmaxf(nm, m_part[s * HW + j]);
    float lv = 0.f;
    #pragma unroll
    for (int s = 0; s < 8; ++s)
        lv += l_part[s * HW + j] * __expf(m_part[s * HW + j] - nm);
    muS[j] = -(nm + logf(lv)) * 1.44269504f;
}

// ------------------------------------------------------------------
// kP: materialize Pt[q][p] = exp2(S*log2e + muS[p]) in bf16.
// Block = 64p x 128q (4 waves x 32q). Grid = 144 x 72 = 10368.
// ------------------------------------------------------------------
__global__ __launch_bounds__(256) void kP(
        const ushort_t* __restrict__ Gbt, const float* __restrict__ muS,
        ushort_t* __restrict__ Pt) {
    const int t = threadIdx.x;
    const int w = t >> 6;
    const int l15 = t & 15, lg = (t >> 4) & 3;
    const int pb = blockIdx.x / 72, qb = blockIdx.x % 72;
    const int p0 = pb * 64;
    const int q0 = qb * 128 + w * 32;
    bf16x8 bq0 = *(const bf16x8*)&Gbt[(q0 + l15) * 32 + lg * 8];
    bf16x8 bq1 = *(const bf16x8*)&Gbt[(q0 + 16 + l15) * 32 + lg * 8];
    bf16x8 ap[4];
    #pragma unroll
    for (int pm = 0; pm < 4; ++pm)
        ap[pm] = *(const bf16x8*)&Gbt[(p0 + pm * 16 + l15) * 32 + lg * 8];
    #pragma unroll
    for (int pm = 0; pm < 4; ++pm) {
        f32x4 z = {0.f,0.f,0.f,0.f};
        f32x4 s0 = __builtin_amdgcn_mfma_f32_16x16x32_bf16(ap[pm], bq0, z, 0,0,0);
        f32x4 s1 = __builtin_amdgcn_mfma_f32_16x16x32_bf16(ap[pm], bq1, z, 0,0,0);
        const int pcol = p0 + pm * 16 + lg * 4;
        float4 mu = *(const float4*)&muS[pcol];
        uint2 u0, u1;
        u0.x = cvtpk_bf16(pexp(s0[0], mu.x), pexp(s0[1], mu.y));
        u0.y = cvtpk_bf16(pexp(s0[2], mu.z), pexp(s0[3], mu.w));
        u1.x = cvtpk_bf16(pexp(s1[0], mu.x), pexp(s1[1], mu.y));
        u1.y = cvtpk_bf16(pexp(s1[2], mu.z), pexp(s1[3], mu.w));
        *(uint2*)&Pt[(size_t)(q0 + l15) * HW + pcol]      = u0;
        *(uint2*)&Pt[(size_t)(q0 + 16 + l15) * HW + pcol] = u1;
    }
}

// ------------------------------------------------------------------
// k3g: pure streaming GEMM Z[c,q] += sum_p xtile[c,p] * Pt[q,p].
// Grid = 144 q-blocks(64) x 8 p-splits = 1152 x 256 (4 waves).
// Wave = 64c x 64q, k32 steps, NO LDS, NO barriers, NO exp.
// ------------------------------------------------------------------
__global__ __launch_bounds__(256) void k3g(
        const ushort_t* __restrict__ xtile, const ushort_t* __restrict__ Pt,
        float* __restrict__ Z) {
    const int t = threadIdx.x;
    const int w = t >> 6;
    const int l15 = t & 15, lg = (t >> 4) & 3;
    const int qb = blockIdx.x % 144, ps = blockIdx.x / 144;
    const int q0 = qb * 64;
    const int cbase = w * 64;
    f32x4 acc[4][4];
    #pragma unroll
    for (int ci = 0; ci < 4; ++ci)
        #pragma unroll
        for (int qn = 0; qn < 4; ++qn) acc[ci][qn] = (f32x4){0.f,0.f,0.f,0.f};
    const int tile0 = ps * 36;             // 36 k32-steps per block
    const size_t prow0 = (size_t)(q0 + l15) * HW;

    for (int it = 0; it < 36; ++it) {
        const int p = ps * 1152 + it * 32;
        const ushort_t* xa =
            &xtile[((size_t)(tile0 + it) * 256 + cbase + l15) * 32 + lg * 8];
        bf16x8 a0 = *(const bf16x8*)&xa[0];
        bf16x8 a1 = *(const bf16x8*)&xa[512];
        bf16x8 a2 = *(const bf16x8*)&xa[1024];
        bf16x8 a3 = *(const bf16x8*)&xa[1536];
        const ushort_t* pb = &Pt[prow0 + p + lg * 8];
        bf16x8 b0 = *(const bf16x8*)&pb[0];
        bf16x8 b1 = *(const bf16x8*)&pb[16 * HW];
        bf16x8 b2 = *(const bf16x8*)&pb[32 * HW];
        bf16x8 b3 = *(const bf16x8*)&pb[48 * HW];
        acc[0][0] = __builtin_amdgcn_mfma_f32_16x16x32_bf16(a0, b0, acc[0][0], 0,0,0);
        acc[1][0] = __builtin_amdgcn_mfma_f32_16x16x32_bf16(a1, b0, acc[1][0], 0,0,0);
        acc[2][0] = __builtin_amdgcn_mfma_f32_16x16x32_bf16(a2, b0, acc[2][0], 0,0,0);
        acc[3][0] = __builtin_amdgcn_mfma_f32_16x16x32_bf16(a3, b0, acc[3][0], 0,0,0);
        acc[0][1] = __builtin_amdgcn_mfma_f32_16x16x32_bf16(a0, b1, acc[0][1], 0,0,0);
        acc[1][1] = __builtin_amdgcn_mfma_f32_16x16x32_bf16(a1, b1, acc[1][1], 0,0,0);
        acc[2][1] = __builtin_amdgcn_mfma_f32_16x16x32_bf16(a2, b1, acc[2][1], 0,0,0);
        acc[3][1] = __builtin_amdgcn_mfma_f32_16x16x32_bf16(a3, b1, acc[3][1], 0,0,0);
        acc[0][2] = __builtin_amdgcn_mfma_f32_16x16x32_bf16(a0, b2, acc[0][2], 0,0,0);
        acc[1][2] = __builtin_amdgcn_mfma_f32_16x16x32_bf16(a1, b2, acc[1][2], 0,0,0);
        acc[2][2] = __builtin_amdgcn_mfma_f32_16x16x32_bf16(a2, b2, acc[2][2], 0,0,0);
        acc[3][2] = __builtin_amdgcn_mfma_f32_16x16x32_bf16(a3, b2, acc[3][2], 0,0,0);
        acc[0][3] = __builtin_amdgcn_mfma_f32_16x16x32_bf16(a0, b3, acc[0][3], 0,0,0);
        acc[1][3] = __builtin_amdgcn_mfma_f32_16x16x32_bf16(a1, b3, acc[1][3], 0,0,0);
        acc[2][3] = __builtin_amdgcn_mfma_f32_16x16x32_bf16(a2, b3, acc[2][3], 0,0,0);
        acc[3][3] = __builtin_amdgcn_mfma_f32_16x16x32_bf16(a3, b3, acc[3][3], 0,0,0);
    }
    #pragma unroll
    for (int ci = 0; ci < 4; ++ci) {
        const int crow = cbase + ci * 16 + lg * 4;
        #pragma unroll
        for (int r = 0; r < 4; ++r) {
            float* zr = &Z[(size_t)(crow + r) * HW + q0 + l15];
            #pragma unroll
            for (int qn = 0; qn < 4; ++qn)
                atomicAdd(zr + qn * 16, acc[ci][qn][r]);
        }
    }
}

// ------------------------------------------------------------------
// k3_pv: FALLBACK (r8 path) when ws_size can't hold Pt.
// ------------------------------------------------------------------
__global__ __launch_bounds__(256, 4) void k3_pv(
        const ushort_t* __restrict__ xtile, const ushort_t* __restrict__ Gbt,
        const float* __restrict__ muS, float* __restrict__ Z) {
    __shared__ ushort_t Pw[4][32][PROW];   // wave-private [q][p] regions
    const int t = threadIdx.x;
    const int w = t >> 6;
    const int l15 = t & 15, lg = (t >> 4) & 3;
    const int qb = blockIdx.x % 288, ps = blockIdx.x / 288;
    const int q0 = qb * 32;
    const int cbase = w * 64;
    bf16x8 bq0 = *(const bf16x8*)&Gbt[(q0 + l15) * 32 + lg * 8];
    bf16x8 bq1 = *(const bf16x8*)&Gbt[(q0 + 16 + l15) * 32 + lg * 8];
    f32x4 acc[4][2];
    #pragma unroll
    for (int ci = 0; ci < 4; ++ci) {
        acc[ci][0] = (f32x4){0.f,0.f,0.f,0.f};
        acc[ci][1] = (f32x4){0.f,0.f,0.f,0.f};
    }
    const int p0beg = ps * (NI * 64);
    const int tile0 = ps * (NI * 2);
    ushort_t* pw = &Pw[w][0][0];
    bf16x8 ap[4];
    #pragma unroll
    for (int pm = 0; pm < 4; ++pm)
        ap[pm] = *(const bf16x8*)&Gbt[(p0beg + pm * 16 + l15) * 32 + lg * 8];

    for (int it = 0; it < NI; ++it) {
        const int p0 = p0beg + it * 64;
        const ushort_t* xa =
            &xtile[((size_t)(tile0 + 2 * it) * 256 + cbase + l15) * 32 + lg * 8];
        bf16x8 a0[4];
        #pragma unroll
        for (int ci = 0; ci < 4; ++ci)
            a0[ci] = *(const bf16x8*)&xa[ci * 512];
        f32x4 s[4][2];
        #pragma unroll
        for (int pm = 0; pm < 4; ++pm) {
            f32x4 z = {0.f,0.f,0.f,0.f};
            s[pm][0] = __builtin_amdgcn_mfma_f32_16x16x32_bf16(ap[pm], bq0, z, 0,0,0);
            s[pm][1] = __builtin_amdgcn_mfma_f32_16x16x32_bf16(ap[pm], bq1, z, 0,0,0);
        }
        if (it < NI - 1) {
            const int pn = p0 + 64;
            #pragma unroll
            for (int pm = 0; pm < 4; ++pm)
                ap[pm] = *(const bf16x8*)&Gbt[(pn + pm * 16 + l15) * 32 + lg * 8];
        }
        #pragma unroll
        for (int pm = 0; pm < 4; ++pm) {
            float4 mu = *(const float4*)&muS[p0 + pm * 16 + lg * 4];
            #pragma unroll
            for (int qn = 0; qn < 2; ++qn) {
                uint2 u;
                u.x = cvtpk_bf16(pexp(s[pm][qn][0], mu.x),
                                 pexp(s[pm][qn][1], mu.y));
                u.y = cvtpk_bf16(pexp(s[pm][qn][2], mu.z),
                                 pexp(s[pm][qn][3], mu.w));
                *(uint2*)&pw[(qn * 16 + l15) * PROW + pm * 16 + lg * 4] = u;
            }
        }
        bf16x8 a1[4];
        const ushort_t* xa1 = xa + 8192;
        #pragma unroll
        for (int ci = 0; ci < 4; ++ci)
            a1[ci] = *(const bf16x8*)&xa1[ci * 512];
        bf16x8 b00 = *(const bf16x8*)&pw[l15 * PROW + lg * 8];
        bf16x8 b01 = *(const bf16x8*)&pw[(16 + l15) * PROW + lg * 8];
        #pragma unroll
        for (int ci = 0; ci < 4; ++ci) {
            acc[ci][0] = __builtin_amdgcn_mfma_f32_16x16x32_bf16(a0[ci], b00, acc[ci][0], 0,0,0);
            acc[ci][1] = __builtin_amdgcn_mfma_f32_16x16x32_bf16(a0[ci], b01, acc[ci][1], 0,0,0);
        }
        bf16x8 b10 = *(const bf16x8*)&pw[l15 * PROW + 32 + lg * 8];
        bf16x8 b11 = *(const bf16x8*)&pw[(16 + l15) * PROW + 32 + lg * 8];
        #pragma unroll
        for (int ci = 0; ci < 4; ++ci) {
            acc[ci][0] = __builtin_amdgcn_mfma_f32_16x16x32_bf16(a1[ci], b10, acc[ci][0], 0,0,0);
            acc[ci][1] = __builtin_amdgcn_mfma_f32_16x16x32_bf16(a1[ci], b11, acc[ci][1], 0,0,0);
        }
    }
    const int qc0 = q0 + l15;
    #pragma unroll
    for (int ci = 0; ci < 4; ++ci) {
        const int crow = cbase + ci * 16 + lg * 4;
        #pragma unroll
        for (int r = 0; r < 4; ++r) {
            float* zr = &Z[(size_t)(crow + r) * HW + qc0];
            atomicAdd(zr,      acc[ci][0][r]);
            atomicAdd(zr + 16, acc[ci][1][r]);
        }
    }
}

// ------------------------------------------------------------------
// k4: per-c row softmax of Z (9216) fused with final softmax over W.
// ------------------------------------------------------------------
__global__ __launch_bounds__(512) void k4_softmax(
        const float* __restrict__ x, float* __restrict__ ZO) {
    __shared__ float zrow[HW];
    __shared__ float red[8];
    int t = threadIdx.x, c = blockIdx.x;
    int lane = t & 63, wid = t >> 6;
    const float* Zr = &ZO[(size_t)c * HW];
    float lm = -INFINITY;
    #pragma unroll
    for (int k = 0; k < 18; ++k) {
        float v = Zr[t + 512 * k];
        zrow[t + 512 * k] = v;
        lm = fmaxf(lm, v);
    }
    #pragma unroll
    for (int off = 32; off; off >>= 1) lm = fmaxf(lm, __shfl_xor(lm, off));
    if (lane == 0) red[wid] = lm;
    __syncthreads();
    float M = fmaxf(fmaxf(fmaxf(red[0], red[1]), fmaxf(red[2], red[3])),
                    fmaxf(fmaxf(red[4], red[5]), fmaxf(red[6], red[7])));
    __syncthreads();
    float ls = 0.f;
    #pragma unroll
    for (int k = 0; k < 18; ++k) {
        int i = t + 512 * k;
        float e = __expf(zrow[i] - M);
        zrow[i] = e;
        ls += e;
    }
    #pragma unroll
    for (int off = 32; off; off >>= 1) ls += __shfl_xor(ls, off);
    if (lane == 0) red[wid] = ls;
    __syncthreads();
    float rS = 1.0f / (red[0] + red[1] + red[2] + red[3]
                     + red[4] + red[5] + red[6] + red[7]);
    const float* xr = &x[(size_t)c * HW];
    float* outr = &ZO[(size_t)c * HW];
    for (int kk = 0; kk < 12; ++kk) {
        int h = wid + kk * 8;
        int base = h * 96;
        float v0 = fmaf(zrow[base + lane], rS, xr[base + lane]);
        float v1 = (lane < 32)
                 ? fmaf(zrow[base + 64 + lane], rS, xr[base + 64 + lane])
                 : -INFINITY;
        float mm = fmaxf(v0, v1);
        #pragma unroll
        for (int off = 32; off; off >>= 1) mm = fmaxf(mm, __shfl_xor(mm, off));
        float e0 = __expf(v0 - mm);
        float e1 = (lane < 32) ? __expf(v1 - mm) : 0.f;
        float ss = e0 + e1;
        #pragma unroll
        for (int off = 32; off; off >>= 1) ss += __shfl_xor(ss, off);
        float r = 1.0f / ss;
        outr[base + lane] = e0 * r;
        if (lane < 32) outr[base + 64 + lane] = e1 * r;
    }
}

extern "C" void kernel_launch(void* const* d_in, const int* in_sizes, int n_in,
                              void* d_out, int out_size, void* d_ws, size_t ws_size,
                              hipStream_t stream) {
    const float* x  = (const float*)d_in[0];   // [256,96,96]
    const float* wc = (const float*)d_in[1];   // [32,256]
    const float* bc = (const float*)d_in[2];   // [32]
    float* Z = (float*)d_out;                  // accum Z, then final out

    float* m_part = (float*)d_ws;              // 8*9216
    float* l_part = m_part + 8 * HW;           // 8*9216
    float* muS    = l_part + 8 * HW;           // 9216
    ushort_t* xtile = (ushort_t*)(muS + HW);   // 288*256*32 bf16
    ushort_t* Gbt   = xtile + 256 * HW;        // 9216*32 bf16
    ushort_t* Pt    = Gbt + 32 * HW;           // 9216*9216 bf16 (162MB)

    const size_t need = 17u * HW * sizeof(float)
                      + ((size_t)256 * HW + 32u * HW + (size_t)HW * HW)
                        * sizeof(ushort_t);

    k1_conv   <<<288,  256, 0, stream>>>(x, wc, bc, Gbt, xtile);
    k2_stats  <<<1152, 512, 0, stream>>>(Gbt, m_part, l_part);
    k2b_merge <<<36,   256, 0, stream>>>(m_part, l_part, muS);
    hipMemsetAsync(Z, 0, (size_t)out_size * sizeof(float), stream);
    if (ws_size >= need) {
        kP  <<<10368, 256, 0, stream>>>(Gbt, muS, Pt);
        k3g <<<1152,  256, 0, stream>>>(xtile, Pt, Z);
    } else {
        k3_pv <<<2304, 256, 0, stream>>>(xtile, Gbt, muS, Z);
    }
    k4_softmax<<<256, 512, 0, stream>>>(x, Z);
}

// Round 10
// 228.532 us; speedup vs baseline: 1.2431x; 1.2431x over previous
//
#include <hip/hip_runtime.h>
#include <math.h>

#define HW 9216   // 96*96
#define NI 18     // 64-p steps per fallback-k3 block
#define PROW 72   // ushorts per P-row in fallback LDS

typedef __attribute__((ext_vector_type(8))) short bf16x8;
typedef __attribute__((ext_vector_type(4))) float f32x4;
typedef unsigned short ushort_t;
typedef unsigned int uint_t;

__device__ __forceinline__ ushort_t f2bf(float f) {
    union { float f; uint_t u; } v; v.f = f;
    uint_t u = v.u + 0x7FFF + ((v.u >> 16) & 1);   // RNE
    return (ushort_t)(u >> 16);
}

__device__ __forceinline__ uint_t cvtpk_bf16(float lo, float hi) {
    uint_t r;
    asm("v_cvt_pk_bf16_f32 %0, %1, %2" : "=v"(r) : "v"(lo), "v"(hi));
    return r;
}

// P = exp(S - m)/l = exp2(S*log2e + muS), muS = -(m + ln l)*log2e
__device__ __forceinline__ float pexp(float s, float mu) {
    return exp2f(fmaf(s, 1.44269504f, mu));
}

// async global -> LDS, 16B per lane (dest = wave-uniform base + lane*16)
__device__ __forceinline__ void gload_lds16(const ushort_t* g, ushort_t* l) {
    __builtin_amdgcn_global_load_lds(
        (const __attribute__((address_space(1))) void*)g,
        (__attribute__((address_space(3))) void*)l, 16, 0, 0);
}

// ------------------------------------------------------------------
// k1: 1x1 conv -> Gbt[p][o] bf16 (p = w*96+h permuted, o contiguous)
//     + xtile[jt][c][32] bf16
// ------------------------------------------------------------------
__global__ __launch_bounds__(256) void k1_conv(
        const float* __restrict__ x, const float* __restrict__ wc,
        const float* __restrict__ bc, ushort_t* __restrict__ Gbt,
        ushort_t* __restrict__ xtile) {
    __shared__ float wt[256][32];          // [c][o] 32KB
    __shared__ float red[8][32][33];       // [cg][px][o] padded
    int t = threadIdx.x;
    int jt = blockIdx.x;
    for (int i = t; i < 256 * 32; i += 256) {
        int o = i >> 8, c = i & 255;       // wc is [o][c]
        wt[c][o] = wc[i];
    }
    __syncthreads();
    int px = t & 31, cg = t >> 5;
    int n = jt * 32 + px;
    float acc[32];
    #pragma unroll
    for (int o = 0; o < 32; ++o) acc[o] = 0.f;
    int c0 = cg * 32;
    ushort_t* xt_out = &xtile[(size_t)jt * 8192 + px];
    for (int cc = 0; cc < 32; ++cc) {
        int c = c0 + cc;
        float xv = x[c * HW + n];
        xt_out[c * 32] = f2bf(xv);         // fused xtile emission
        #pragma unroll
        for (int o4 = 0; o4 < 8; ++o4) {
            float4 wv = *(const float4*)&wt[c][o4 * 4];
            acc[o4*4+0] = fmaf(wv.x, xv, acc[o4*4+0]);
            acc[o4*4+1] = fmaf(wv.y, xv, acc[o4*4+1]);
            acc[o4*4+2] = fmaf(wv.z, xv, acc[o4*4+2]);
            acc[o4*4+3] = fmaf(wv.w, xv, acc[o4*4+3]);
        }
    }
    #pragma unroll
    for (int o = 0; o < 32; ++o) red[cg][px][o] = acc[o];
    __syncthreads();
    int px2 = t >> 3, o2 = (t & 7) * 4;
    float s[4] = {0.f, 0.f, 0.f, 0.f};
    #pragma unroll
    for (int g = 0; g < 8; ++g) {
        s[0] += red[g][px2][o2 + 0];
        s[1] += red[g][px2][o2 + 1];
        s[2] += red[g][px2][o2 + 2];
        s[3] += red[g][px2][o2 + 3];
    }
    int n2 = jt * 32 + px2;
    int h = n2 / 96, w = n2 % 96;
    int p = w * 96 + h;
    uint2 pk;
    pk.x = (uint_t)f2bf(s[0] + bc[o2+0]) | ((uint_t)f2bf(s[1] + bc[o2+1]) << 16);
    pk.y = (uint_t)f2bf(s[2] + bc[o2+2]) | ((uint_t)f2bf(s[3] + bc[o2+3]) << 16);
    *(uint2*)&Gbt[p * 32 + o2] = pk;
}

// ------------------------------------------------------------------
// k2: per-row online softmax stats of S = G^T G via bf16 MFMA.
// ------------------------------------------------------------------
__global__ __launch_bounds__(512) void k2_stats(
        const ushort_t* __restrict__ Gbt, float* __restrict__ m_part,
        float* __restrict__ l_part) {
    __shared__ float mred[2][64], lred[2][64];
    int t = threadIdx.x;
    int w = t >> 6, l = t & 63;
    int l15 = l & 15, lg = l >> 4;
    int jb = blockIdx.x % 144, qs = blockIdx.x / 144;
    int j0 = jb * 64;
    int rf = w & 3, qp = w >> 2;
    bf16x8 aj = *(const bf16x8*)&Gbt[(j0 + rf * 16 + l15) * 32 + lg * 8];
    float m[4], lsum[4];
    #pragma unroll
    for (int r = 0; r < 4; ++r) { m[r] = -INFINITY; lsum[r] = 0.f; }
    int qbeg = qs * 1152;
    for (int tq = 0; tq < 18; ++tq) {
        int q0 = qbeg + tq * 64;
        bf16x8 b0 = *(const bf16x8*)&Gbt[(q0 + qp * 32 + l15) * 32 + lg * 8];
        bf16x8 b1 = *(const bf16x8*)&Gbt[(q0 + qp * 32 + 16 + l15) * 32 + lg * 8];
        f32x4 s0 = {0.f,0.f,0.f,0.f}, s1 = {0.f,0.f,0.f,0.f};
        s0 = __builtin_amdgcn_mfma_f32_16x16x32_bf16(aj, b0, s0, 0, 0, 0);
        s1 = __builtin_amdgcn_mfma_f32_16x16x32_bf16(aj, b1, s1, 0, 0, 0);
        #pragma unroll
        for (int r = 0; r < 4; ++r) {
            float tm = fmaxf(s0[r], s1[r]);
            float nm = fmaxf(m[r], tm);
            lsum[r] = lsum[r] * __expf(m[r] - nm)
                    + __expf(s0[r] - nm) + __expf(s1[r] - nm);
            m[r] = nm;
        }
    }
    #pragma unroll
    for (int off = 1; off < 16; off <<= 1) {
        #pragma unroll
        for (int r = 0; r < 4; ++r) {
            float mo = __shfl_xor(m[r], off);
            float lo = __shfl_xor(lsum[r], off);
            float nm = fmaxf(m[r], mo);
            lsum[r] = lsum[r] * __expf(m[r] - nm) + lo * __expf(mo - nm);
            m[r] = nm;
        }
    }
    if (l15 == 0) {
        #pragma unroll
        for (int r = 0; r < 4; ++r) {
            mred[qp][rf * 16 + lg * 4 + r] = m[r];
            lred[qp][rf * 16 + lg * 4 + r] = lsum[r];
        }
    }
    __syncthreads();
    if (t < 64) {
        float m0 = mred[0][t], m1 = mred[1][t];
        float l0 = lred[0][t], l1 = lred[1][t];
        float nm = fmaxf(m0, m1);
        float lv = l0 * __expf(m0 - nm) + l1 * __expf(m1 - nm);
        m_part[qs * HW + j0 + t] = nm;
        l_part[qs * HW + j0 + t] = lv;
    }
}

// merge 8 q-split partials -> muS = -(m + ln l) * log2e
__global__ __launch_bounds__(256) void k2b_merge(
        const float* __restrict__ m_part, const float* __restrict__ l_part,
        float* __restrict__ muS) {
    int j = blockIdx.x * 256 + threadIdx.x;
    float nm = -INFINITY;
    #pragma unroll
    for (int s = 0; s < 8; ++s) nm = fmaxf(nm, m_part[s * HW + j]);
    float lv = 0.f;
    #pragma unroll
    for (int s = 0; s < 8; ++s)
        lv += l_part[s * HW + j] * __expf(m_part[s * HW + j] - nm);
    muS[j] = -(nm + logf(lv)) * 1.44269504f;
}

// ------------------------------------------------------------------
// kP: materialize P in TILED layout: Pt[slab=p/32][q][p%32] bf16.
// Block = 64p x 128q (4 waves x 32q). Grid = 144 x 72 = 10368.
// ------------------------------------------------------------------
__global__ __launch_bounds__(256) void kP(
        const ushort_t* __restrict__ Gbt, const float* __restrict__ muS,
        ushort_t* __restrict__ Pt) {
    const int t = threadIdx.x;
    const int w = t >> 6;
    const int l15 = t & 15, lg = (t >> 4) & 3;
    const int pb = blockIdx.x / 72, qb = blockIdx.x % 72;
    const int p0 = pb * 64;
    const int q0 = qb * 128 + w * 32;
    bf16x8 bq0 = *(const bf16x8*)&Gbt[(q0 + l15) * 32 + lg * 8];
    bf16x8 bq1 = *(const bf16x8*)&Gbt[(q0 + 16 + l15) * 32 + lg * 8];
    bf16x8 ap[4];
    #pragma unroll
    for (int pm = 0; pm < 4; ++pm)
        ap[pm] = *(const bf16x8*)&Gbt[(p0 + pm * 16 + l15) * 32 + lg * 8];
    #pragma unroll
    for (int pm = 0; pm < 4; ++pm) {
        f32x4 z = {0.f,0.f,0.f,0.f};
        f32x4 s0 = __builtin_amdgcn_mfma_f32_16x16x32_bf16(ap[pm], bq0, z, 0,0,0);
        f32x4 s1 = __builtin_amdgcn_mfma_f32_16x16x32_bf16(ap[pm], bq1, z, 0,0,0);
        const int pcol = pm * 16 + lg * 4;         // 0..63 within block
        float4 mu = *(const float4*)&muS[p0 + pcol];
        uint2 u0, u1;
        u0.x = cvtpk_bf16(pexp(s0[0], mu.x), pexp(s0[1], mu.y));
        u0.y = cvtpk_bf16(pexp(s0[2], mu.z), pexp(s0[3], mu.w));
        u1.x = cvtpk_bf16(pexp(s1[0], mu.x), pexp(s1[1], mu.y));
        u1.y = cvtpk_bf16(pexp(s1[2], mu.z), pexp(s1[3], mu.w));
        const int slab = (p0 + pcol) >> 5;
        const int pp   = pcol & 31;
        ushort_t* base = &Pt[((size_t)slab * HW + q0 + l15) * 32 + pp];
        *(uint2*)base            = u0;             // q = q0+l15
        *(uint2*)(base + 16*32)  = u1;             // q = q0+16+l15
    }
}

// ------------------------------------------------------------------
// k3g: streaming GEMM Z[c,q] += sum_p xtile[c,p] * P[p,q].
// Grid = 144 q-blocks(64) x 8 p-splits = 1152 x 512 (8 waves).
// Wave = 64c x 32q. B staged via global_load_lds (coalesced, dbuf,
// XOR chunk-swizzle both sides), one barrier per k64 iter (m97 pattern).
// ------------------------------------------------------------------
__global__ __launch_bounds__(512) void k3g(
        const ushort_t* __restrict__ xtile, const ushort_t* __restrict__ Pt,
        float* __restrict__ Z) {
    __shared__ ushort_t Pl[2][2][64][32];  // [buf][half][q][pp] 16KB
    const int t = threadIdx.x;
    const int w = t >> 6;
    const int l15 = t & 15, lg = (t >> 4) & 3;
    const int qb = blockIdx.x % 144, ps = blockIdx.x / 144;
    const int q0 = qb * 64;
    const int cg = w & 3, qh = w >> 2;
    const int cbase = cg * 64;
    const int slab0 = ps * 36;

    // staging decomposition (constant per thread)
    const int s_half = t >> 8;
    const int s_q    = (t & 255) >> 2;
    const int s_chp  = t & 3;                        // physical chunk
    const int s_chl  = s_chp ^ ((s_q >> 1) & 3);     // logical chunk (swizzle)
    // B-read row + swizzled chunk offset (same for qn=0,1 since +16 keeps (q>>1)&3)
    const int qr0  = qh * 32 + l15;
    const int coff = (lg ^ ((qr0 >> 1) & 3)) * 8;    // ushorts

    f32x4 acc[4][2];
    #pragma unroll
    for (int ci = 0; ci < 4; ++ci) {
        acc[ci][0] = (f32x4){0.f,0.f,0.f,0.f};
        acc[ci][1] = (f32x4){0.f,0.f,0.f,0.f};
    }

    #define STAGE(B, IT) do {                                                  \
        const ushort_t* _src = &Pt[((size_t)(slab0 + (IT) * 2 + s_half) * HW   \
                                    + q0 + s_q) * 32 + s_chl * 8];             \
        gload_lds16(_src, &Pl[B][s_half][s_q][s_chp * 8]);                     \
    } while (0)

    STAGE(0, 0);
    int cur = 0;
    for (int it = 0; it < 18; ++it) {
        __syncthreads();                   // buf[cur] staged (vmcnt drained)
        if (it < 17) STAGE(cur ^ 1, it + 1);   // in flight across compute
        #pragma unroll
        for (int h = 0; h < 2; ++h) {
            const size_t tix = (size_t)(slab0 + it * 2 + h) * 256;
            const ushort_t* xa = &xtile[(tix + cbase + l15) * 32 + lg * 8];
            bf16x8 a0 = *(const bf16x8*)&xa[0];
            bf16x8 a1 = *(const bf16x8*)&xa[512];
            bf16x8 a2 = *(const bf16x8*)&xa[1024];
            bf16x8 a3 = *(const bf16x8*)&xa[1536];
            bf16x8 b0 = *(const bf16x8*)&Pl[cur][h][qr0][coff];
            bf16x8 b1 = *(const bf16x8*)&Pl[cur][h][qr0 + 16][coff];
            acc[0][0] = __builtin_amdgcn_mfma_f32_16x16x32_bf16(a0, b0, acc[0][0], 0,0,0);
            acc[1][0] = __builtin_amdgcn_mfma_f32_16x16x32_bf16(a1, b0, acc[1][0], 0,0,0);
            acc[2][0] = __builtin_amdgcn_mfma_f32_16x16x32_bf16(a2, b0, acc[2][0], 0,0,0);
            acc[3][0] = __builtin_amdgcn_mfma_f32_16x16x32_bf16(a3, b0, acc[3][0], 0,0,0);
            acc[0][1] = __builtin_amdgcn_mfma_f32_16x16x32_bf16(a0, b1, acc[0][1], 0,0,0);
            acc[1][1] = __builtin_amdgcn_mfma_f32_16x16x32_bf16(a1, b1, acc[1][1], 0,0,0);
            acc[2][1] = __builtin_amdgcn_mfma_f32_16x16x32_bf16(a2, b1, acc[2][1], 0,0,0);
            acc[3][1] = __builtin_amdgcn_mfma_f32_16x16x32_bf16(a3, b1, acc[3][1], 0,0,0);
        }
        cur ^= 1;
    }
    #undef STAGE
    const int qcol = q0 + qh * 32 + l15;
    #pragma unroll
    for (int ci = 0; ci < 4; ++ci) {
        const int crow = cbase + ci * 16 + lg * 4;
        #pragma unroll
        for (int r = 0; r < 4; ++r) {
            float* zr = &Z[(size_t)(crow + r) * HW + qcol];
            atomicAdd(zr,      acc[ci][0][r]);
            atomicAdd(zr + 16, acc[ci][1][r]);
        }
    }
}

// ------------------------------------------------------------------
// k3_pv: FALLBACK (r8 path) when ws_size can't hold Pt.
// ------------------------------------------------------------------
__global__ __launch_bounds__(256, 4) void k3_pv(
        const ushort_t* __restrict__ xtile, const ushort_t* __restrict__ Gbt,
        const float* __restrict__ muS, float* __restrict__ Z) {
    __shared__ ushort_t Pw[4][32][PROW];   // wave-private [q][p] regions
    const int t = threadIdx.x;
    const int w = t >> 6;
    const int l15 = t & 15, lg = (t >> 4) & 3;
    const int qb = blockIdx.x % 288, ps = blockIdx.x / 288;
    const int q0 = qb * 32;
    const int cbase = w * 64;
    bf16x8 bq0 = *(const bf16x8*)&Gbt[(q0 + l15) * 32 + lg * 8];
    bf16x8 bq1 = *(const bf16x8*)&Gbt[(q0 + 16 + l15) * 32 + lg * 8];
    f32x4 acc[4][2];
    #pragma unroll
    for (int ci = 0; ci < 4; ++ci) {
        acc[ci][0] = (f32x4){0.f,0.f,0.f,0.f};
        acc[ci][1] = (f32x4){0.f,0.f,0.f,0.f};
    }
    const int p0beg = ps * (NI * 64);
    const int tile0 = ps * (NI * 2);
    ushort_t* pw = &Pw[w][0][0];
    bf16x8 ap[4];
    #pragma unroll
    for (int pm = 0; pm < 4; ++pm)
        ap[pm] = *(const bf16x8*)&Gbt[(p0beg + pm * 16 + l15) * 32 + lg * 8];

    for (int it = 0; it < NI; ++it) {
        const int p0 = p0beg + it * 64;
        const ushort_t* xa =
            &xtile[((size_t)(tile0 + 2 * it) * 256 + cbase + l15) * 32 + lg * 8];
        bf16x8 a0[4];
        #pragma unroll
        for (int ci = 0; ci < 4; ++ci)
            a0[ci] = *(const bf16x8*)&xa[ci * 512];
        f32x4 s[4][2];
        #pragma unroll
        for (int pm = 0; pm < 4; ++pm) {
            f32x4 z = {0.f,0.f,0.f,0.f};
            s[pm][0] = __builtin_amdgcn_mfma_f32_16x16x32_bf16(ap[pm], bq0, z, 0,0,0);
            s[pm][1] = __builtin_amdgcn_mfma_f32_16x16x32_bf16(ap[pm], bq1, z, 0,0,0);
        }
        if (it < NI - 1) {
            const int pn = p0 + 64;
            #pragma unroll
            for (int pm = 0; pm < 4; ++pm)
                ap[pm] = *(const bf16x8*)&Gbt[(pn + pm * 16 + l15) * 32 + lg * 8];
        }
        #pragma unroll
        for (int pm = 0; pm < 4; ++pm) {
            float4 mu = *(const float4*)&muS[p0 + pm * 16 + lg * 4];
            #pragma unroll
            for (int qn = 0; qn < 2; ++qn) {
                uint2 u;
                u.x = cvtpk_bf16(pexp(s[pm][qn][0], mu.x),
                                 pexp(s[pm][qn][1], mu.y));
                u.y = cvtpk_bf16(pexp(s[pm][qn][2], mu.z),
                                 pexp(s[pm][qn][3], mu.w));
                *(uint2*)&pw[(qn * 16 + l15) * PROW + pm * 16 + lg * 4] = u;
            }
        }
        bf16x8 a1[4];
        const ushort_t* xa1 = xa + 8192;
        #pragma unroll
        for (int ci = 0; ci < 4; ++ci)
            a1[ci] = *(const bf16x8*)&xa1[ci * 512];
        bf16x8 b00 = *(const bf16x8*)&pw[l15 * PROW + lg * 8];
        bf16x8 b01 = *(const bf16x8*)&pw[(16 + l15) * PROW + lg * 8];
        #pragma unroll
        for (int ci = 0; ci < 4; ++ci) {
            acc[ci][0] = __builtin_amdgcn_mfma_f32_16x16x32_bf16(a0[ci], b00, acc[ci][0], 0,0,0);
            acc[ci][1] = __builtin_amdgcn_mfma_f32_16x16x32_bf16(a0[ci], b01, acc[ci][1], 0,0,0);
        }
        bf16x8 b10 = *(const bf16x8*)&pw[l15 * PROW + 32 + lg * 8];
        bf16x8 b11 = *(const bf16x8*)&pw[(16 + l15) * PROW + 32 + lg * 8];
        #pragma unroll
        for (int ci = 0; ci < 4; ++ci) {
            acc[ci][0] = __builtin_amdgcn_mfma_f32_16x16x32_bf16(a1[ci], b10, acc[ci][0], 0,0,0);
            acc[ci][1] = __builtin_amdgcn_mfma_f32_16x16x32_bf16(a1[ci], b11, acc[ci][1], 0,0,0);
        }
    }
    const int qc0 = q0 + l15;
    #pragma unroll
    for (int ci = 0; ci < 4; ++ci) {
        const int crow = cbase + ci * 16 + lg * 4;
        #pragma unroll
        for (int r = 0; r < 4; ++r) {
            float* zr = &Z[(size_t)(crow + r) * HW + qc0];
            atomicAdd(zr,      acc[ci][0][r]);
            atomicAdd(zr + 16, acc[ci][1][r]);
        }
    }
}

// ------------------------------------------------------------------
// k4: per-c row softmax of Z (9216) fused with final softmax over W.
// ------------------------------------------------------------------
__global__ __launch_bounds__(512) void k4_softmax(
        const float* __restrict__ x, float* __restrict__ ZO) {
    __shared__ float zrow[HW];
    __shared__ float red[8];
    int t = threadIdx.x, c = blockIdx.x;
    int lane = t & 63, wid = t >> 6;
    const float* Zr = &ZO[(size_t)c * HW];
    float lm = -INFINITY;
    #pragma unroll
    for (int k = 0; k < 18; ++k) {
        float v = Zr[t + 512 * k];
        zrow[t + 512 * k] = v;
        lm = fmaxf(lm, v);
    }
    #pragma unroll
    for (int off = 32; off; off >>= 1) lm = fmaxf(lm, __shfl_xor(lm, off));
    if (lane == 0) red[wid] = lm;
    __syncthreads();
    float M = fmaxf(fmaxf(fmaxf(red[0], red[1]), fmaxf(red[2], red[3])),
                    fmaxf(fmaxf(red[4], red[5]), fmaxf(red[6], red[7])));
    __syncthreads();
    float ls = 0.f;
    #pragma unroll
    for (int k = 0; k < 18; ++k) {
        int i = t + 512 * k;
        float e = __expf(zrow[i] - M);
        zrow[i] = e;
        ls += e;
    }
    #pragma unroll
    for (int off = 32; off; off >>= 1) ls += __shfl_xor(ls, off);
    if (lane == 0) red[wid] = ls;
    __syncthreads();
    float rS = 1.0f / (red[0] + red[1] + red[2] + red[3]
                     + red[4] + red[5] + red[6] + red[7]);
    const float* xr = &x[(size_t)c * HW];
    float* outr = &ZO[(size_t)c * HW];
    for (int kk = 0; kk < 12; ++kk) {
        int h = wid + kk * 8;
        int base = h * 96;
        float v0 = fmaf(zrow[base + lane], rS, xr[base + lane]);
        float v1 = (lane < 32)
                 ? fmaf(zrow[base + 64 + lane], rS, xr[base + 64 + lane])
                 : -INFINITY;
        float mm = fmaxf(v0, v1);
        #pragma unroll
        for (int off = 32; off; off >>= 1) mm = fmaxf(mm, __shfl_xor(mm, off));
        float e0 = __expf(v0 - mm);
        float e1 = (lane < 32) ? __expf(v1 - mm) : 0.f;
        float ss = e0 + e1;
        #pragma unroll
        for (int off = 32; off; off >>= 1) ss += __shfl_xor(ss, off);
        float r = 1.0f / ss;
        outr[base + lane] = e0 * r;
        if (lane < 32) outr[base + 64 + lane] = e1 * r;
    }
}

extern "C" void kernel_launch(void* const* d_in, const int* in_sizes, int n_in,
                              void* d_out, int out_size, void* d_ws, size_t ws_size,
                              hipStream_t stream) {
    const float* x  = (const float*)d_in[0];   // [256,96,96]
    const float* wc = (const float*)d_in[1];   // [32,256]
    const float* bc = (const float*)d_in[2];   // [32]
    float* Z = (float*)d_out;                  // accum Z, then final out

    float* m_part = (float*)d_ws;              // 8*9216
    float* l_part = m_part + 8 * HW;           // 8*9216
    float* muS    = l_part + 8 * HW;           // 9216
    ushort_t* xtile = (ushort_t*)(muS + HW);   // 288*256*32 bf16
    ushort_t* Gbt   = xtile + 256 * HW;        // 9216*32 bf16
    ushort_t* Pt    = Gbt + 32 * HW;           // 288 slabs x 9216 x 32 bf16

    const size_t need = 17u * HW * sizeof(float)
                      + ((size_t)256 * HW + 32u * HW + (size_t)HW * HW)
                        * sizeof(ushort_t);

    k1_conv   <<<288,  256, 0, stream>>>(x, wc, bc, Gbt, xtile);
    k2_stats  <<<1152, 512, 0, stream>>>(Gbt, m_part, l_part);
    k2b_merge <<<36,   256, 0, stream>>>(m_part, l_part, muS);
    hipMemsetAsync(Z, 0, (size_t)out_size * sizeof(float), stream);
    if (ws_size >= need) {
        kP  <<<10368, 256, 0, stream>>>(Gbt, muS, Pt);
        k3g <<<1152,  512, 0, stream>>>(xtile, Pt, Z);
    } else {
        k3_pv <<<2304, 256, 0, stream>>>(xtile, Gbt, muS, Z);
    }
    k4_softmax<<<256, 512, 0, stream>>>(x, Z);
}